// Round 1
// baseline (614.209 us; speedup 1.0000x reference)
//
#include <hip/hip_runtime.h>

// UAG_RNN v5: v4 + LDS-only barriers in the scan loops (no vmcnt drain per
// step: prefetch loads and output stores stay in flight across s_barrier),
// and colscan biases held in registers instead of per-step LDS reads.
// B=8, C=64, H=128, W=128.

#define B_ 8
#define C_ 64
#define H_ 128
#define W_ 128
#define HW_ (H_*W_)      // 16384
#define CHW_ (C_*HW_)    // 1048576
#define TOT_ (B_*CHW_)   // 8388608

typedef __attribute__((ext_vector_type(8))) short bfrag;
typedef __attribute__((ext_vector_type(4))) float f4_t;

// LDS-ordering barrier: flush own DS ops, then workgroup barrier.
// Deliberately does NOT drain vmcnt — global prefetch loads / stores remain
// in flight across steps (the whole point of this revision).
#define LDS_BARRIER() do { \
    asm volatile("s_waitcnt lgkmcnt(0)" ::: "memory"); \
    __builtin_amdgcn_s_barrier(); \
} while (0)

// Single-wave LDS ordering point (no barrier instruction needed for 1 wave;
// DS ops complete in order within a wave, clobber stops compiler reordering).
#define WAVE_LDS_FENCE() asm volatile("s_waitcnt lgkmcnt(0)" ::: "memory")

__device__ inline unsigned short bfr(float f) {
    unsigned int u = __float_as_uint(f);
    u += 0x7fffu + ((u >> 16) & 1u);
    return (unsigned short)(u >> 16);
}
__device__ inline float b2f(unsigned short u) {
    return __uint_as_float(((unsigned int)u) << 16);
}
__device__ inline bfrag packf(float4 a, float4 b) {
    bfrag r;
    r[0]=(short)bfr(a.x); r[1]=(short)bfr(a.y); r[2]=(short)bfr(a.z); r[3]=(short)bfr(a.w);
    r[4]=(short)bfr(b.x); r[5]=(short)bfr(b.y); r[6]=(short)bfr(b.z); r[7]=(short)bfr(b.w);
    return r;
}
__device__ inline ushort4 pack4(float a, float b, float c, float d) {
    ushort4 r; r.x=bfr(a); r.y=bfr(b); r.z=bfr(c); r.w=bfr(d); return r;
}
// relu on two packed bf16 in a u32
__device__ inline unsigned int relu2(unsigned int w) {
    unsigned int lo = (w & 0x8000u) ? 0u : (w & 0xffffu);
    unsigned int hi = (w & 0x80000000u) ? 0u : (w & 0xffff0000u);
    return lo | hi;
}
__device__ inline uint4 relu8(uint4 v) {
    v.x = relu2(v.x); v.y = relu2(v.y); v.z = relu2(v.z); v.w = relu2(v.w);
    return v;
}

#define MFMA __builtin_amdgcn_mfma_f32_16x16x32_bf16

// x NCHW fp32 -> x2 NHWC bf16 ; y NCHW fp32 -> y2 NHWC fp32
__global__ void k_prep(const float* __restrict__ x, const float* __restrict__ y,
                       float* __restrict__ y2, unsigned short* __restrict__ x2) {
    __shared__ float t[64][65];
    int blk = blockIdx.x;
    int isx = blk >> 11; blk &= 2047;
    int b = blk >> 8, hw0 = (blk & 255) * 64;
    int cq = threadIdx.x >> 6, lo = threadIdx.x & 63;
    const float* ip = (isx ? x : y) + (size_t)b * CHW_;
#pragma unroll
    for (int p = 0; p < 16; p++) {
        int c = p * 4 + cq;
        t[c][lo] = ip[(size_t)c * HW_ + hw0 + lo];
    }
    __syncthreads();
    if (isx) {
        unsigned short* op = x2 + (size_t)b * CHW_;
#pragma unroll
        for (int p = 0; p < 16; p++) {
            int hw = p * 4 + cq;
            op[(size_t)(hw0 + hw) * 64 + lo] = bfr(t[lo][hw]);
        }
    } else {
        float* op = y2 + (size_t)b * CHW_;
#pragma unroll
        for (int p = 0; p < 16; p++) {
            int hw = p * 4 + cq;
            op[(size_t)(hw0 + hw) * 64 + lo] = t[lo][hw];
        }
    }
}

// sum 4 fp32 NHWC dir buffers -> out NCHW fp32
__global__ void k_tb(const float* __restrict__ i0, const float* __restrict__ i1,
                     const float* __restrict__ i2, const float* __restrict__ i3,
                     float* __restrict__ outp) {
    __shared__ float t[64][65];
    int blk = blockIdx.x;
    int b = blk >> 8, hw0 = (blk & 255) * 64;
    int cq = threadIdx.x >> 6, lo = threadIdx.x & 63;
    size_t bb = (size_t)b * CHW_;
#pragma unroll
    for (int p = 0; p < 16; p++) {
        int hw = p * 4 + cq;
        size_t s = bb + (size_t)(hw0 + hw) * 64 + lo;
        t[hw][lo] = i0[s] + i1[s] + i2[s] + i3[s];
    }
    __syncthreads();
    float* op = outp + bb;
#pragma unroll
    for (int p = 0; p < 16; p++) {
        int c = p * 4 + cq;
        op[(size_t)c * HW_ + hw0 + lo] = t[lo][c];
    }
}

// Row scans: grid 128 = s(2) x b(8) x wb(8 of width 16). 1 wave/block.
// h_i = relu(Wa*x_i + ba + (Wb*h_{i-1} + bb) * y_{i-1})
__global__ __launch_bounds__(64) void k_rowscan(
        const unsigned short* __restrict__ x2, const float* __restrict__ y2,
        const float* __restrict__ Wc, const float* __restrict__ bc,
        unsigned short* __restrict__ hs2, unsigned short* __restrict__ hn2) {
    int bid = blockIdx.x;
    int s = bid >> 6, b = (bid >> 3) & 7, wb = bid & 7;
    int w0 = wb * 16;
    int lane = threadIdx.x, q = lane >> 4, n = lane & 15;
    int ka = s ? 8 : 0, kb = ka + 1;

    bfrag WaF[4][2], WbF[4][2];
#pragma unroll
    for (int mt = 0; mt < 4; mt++)
#pragma unroll
        for (int kc = 0; kc < 2; kc++) {
            const float* wp = Wc + (size_t)(ka * 64 + mt * 16 + n) * 64 + kc * 32 + q * 8;
            WaF[mt][kc] = packf(*(const float4*)wp, *(const float4*)(wp + 4));
            const float* wq2 = Wc + (size_t)(kb * 64 + mt * 16 + n) * 64 + kc * 32 + q * 8;
            WbF[mt][kc] = packf(*(const float4*)wq2, *(const float4*)(wq2 + 4));
        }
    f4_t baR[4], bbR[4];
#pragma unroll
    for (int mt = 0; mt < 4; mt++) {
        float4 ta = *(const float4*)&bc[ka * 64 + mt * 16 + q * 4];
        float4 tb = *(const float4*)&bc[kb * 64 + mt * 16 + q * 4];
        baR[mt] = f4_t{ta.x, ta.y, ta.z, ta.w};
        bbR[mt] = f4_t{tb.x, tb.y, tb.z, tb.w};
    }

    const unsigned short* xb = x2 + (size_t)b * CHW_;
    const float* yb = y2 + (size_t)b * CHW_;
    unsigned short* dT = (s ? hn2 : hs2) + (size_t)b * CHW_;

    __shared__ __align__(16) unsigned short stt[2][16][72];

    // init row0: h0 = x[row0] (north: relu'd)
    int row0 = s ? 127 : 0;
    {
        const unsigned short* sp = xb + (size_t)(row0 * 128 + w0 + n) * 64 + q * 16;
        uint4 v0 = *(const uint4*)sp;
        uint4 v1 = *(const uint4*)(sp + 8);
        if (s) { v0 = relu8(v0); v1 = relu8(v1); }
        *(uint4*)&stt[0][n][q * 16] = v0;
        *(uint4*)&stt[0][n][q * 16 + 8] = v1;
        unsigned short* op = dT + (size_t)(row0 * 128 + w0 + n) * 64 + q * 16;
        *(uint4*)op = v0;
        *(uint4*)(op + 8) = v1;
    }

    // prefetch i=1
    uint4 xf0, xf1; float4 yv[4];
    {
        int row1 = s ? 126 : 1;
        const unsigned short* sp = xb + (size_t)(row1 * 128 + w0 + n) * 64 + q * 8;
        xf0 = *(const uint4*)sp;
        xf1 = *(const uint4*)(sp + 32);
#pragma unroll
        for (int mt = 0; mt < 4; mt++)
            yv[mt] = *(const float4*)&yb[(size_t)(row0 * 128 + w0 + n) * 64 + mt * 16 + q * 4];
    }
    WAVE_LDS_FENCE();

    for (int i = 1; i < 128; i++) {
        int row = s ? 127 - i : i;
        int rd = (i - 1) & 1, wr = i & 1;

        bfrag fb0 = *(const bfrag*)&stt[rd][n][q * 8];
        bfrag fb1 = *(const bfrag*)&stt[rd][n][32 + q * 8];
        bfrag fa0 = *(const bfrag*)&xf0;
        bfrag fa1 = *(const bfrag*)&xf1;

        f4_t DA[4], DB[4];
#pragma unroll
        for (int mt = 0; mt < 4; mt++) {
            DA[mt] = MFMA(WaF[mt][0], fa0, baR[mt], 0, 0, 0);
            DA[mt] = MFMA(WaF[mt][1], fa1, DA[mt], 0, 0, 0);
            DB[mt] = MFMA(WbF[mt][0], fb0, bbR[mt], 0, 0, 0);
            DB[mt] = MFMA(WbF[mt][1], fb1, DB[mt], 0, 0, 0);
        }

        uint4 xn0, xn1; float4 yn[4];
        if (i < 127) {
            int rowN = s ? 127 - (i + 1) : i + 1;
            int yrowN = s ? rowN + 1 : rowN - 1;
            const unsigned short* sp = xb + (size_t)(rowN * 128 + w0 + n) * 64 + q * 8;
            xn0 = *(const uint4*)sp;
            xn1 = *(const uint4*)(sp + 32);
#pragma unroll
            for (int mt = 0; mt < 4; mt++)
                yn[mt] = *(const float4*)&yb[(size_t)(yrowN * 128 + w0 + n) * 64 + mt * 16 + q * 4];
        }

#pragma unroll
        for (int mt = 0; mt < 4; mt++) {
            float h0 = fmaxf(DA[mt][0] + DB[mt][0] * yv[mt].x, 0.f);
            float h1 = fmaxf(DA[mt][1] + DB[mt][1] * yv[mt].y, 0.f);
            float h2 = fmaxf(DA[mt][2] + DB[mt][2] * yv[mt].z, 0.f);
            float h3 = fmaxf(DA[mt][3] + DB[mt][3] * yv[mt].w, 0.f);
            ushort4 pk = pack4(h0, h1, h2, h3);
            *(ushort4*)&stt[wr][n][mt * 16 + q * 4] = pk;
            *(ushort4*)&dT[(size_t)(row * 128 + w0 + n) * 64 + mt * 16 + q * 4] = pk;
        }
        if (i < 127) {
            xf0 = xn0; xf1 = xn1;
#pragma unroll
            for (int mt = 0; mt < 4; mt++) yv[mt] = yn[mt];
        }
        WAVE_LDS_FENCE();
    }
}

// Col scans: grid 32 = d(4) x b(8). 512 threads = 8 waves; wave w owns rows
// [16w, 16w+16). Shift coupling entirely in LDS; 1 LDS-only barrier/step
// (dbuf state) — vmcnt (prefetch + output stores) stays in flight.
__global__ __launch_bounds__(512, 2) void k_colscan(
        const float* __restrict__ y2,
        const unsigned short* __restrict__ hs2, const unsigned short* __restrict__ hn2,
        const float* __restrict__ Wc, const float* __restrict__ bc,
        const float* __restrict__ gam,
        float* __restrict__ outD) {
    int bid = blockIdx.x;
    int d = bid >> 3, b = bid & 7;
    int tid = threadIdx.x;
    int wave = tid >> 6, lane = tid & 63, q = lane >> 4, n = lane & 15;
    int row = wave * 16 + n;           // this lane's output row (N-dim)
    int down = (d < 2) ? 1 : 0;
    int flip = d & 1;
    const unsigned short* base2 = ((d < 2) ? hs2 : hn2) + (size_t)b * CHW_;
    int kt, ka, kb;
    if (d == 0)      { kt = 2;  ka = 3;  kb = 4;  }
    else if (d == 1) { kt = 5;  ka = 6;  kb = 7;  }
    else if (d == 2) { kt = 10; ka = 11; kb = 12; }
    else             { kt = 13; ka = 14; kb = 15; }
    float g = gam[d];

    bfrag WA[4][2], WB[4][2], WT[4][2];
#pragma unroll
    for (int mt = 0; mt < 4; mt++)
#pragma unroll
        for (int kc = 0; kc < 2; kc++) {
            const float* wa = Wc + (size_t)(ka * 64 + mt * 16 + n) * 64 + kc * 32 + q * 8;
            const float* wb = Wc + (size_t)(kb * 64 + mt * 16 + n) * 64 + kc * 32 + q * 8;
            const float* wt = Wc + (size_t)(kt * 64 + mt * 16 + n) * 64 + kc * 32 + q * 8;
            WA[mt][kc] = packf(*(const float4*)wa, *(const float4*)(wa + 4));
            WB[mt][kc] = packf(*(const float4*)wb, *(const float4*)(wb + 4));
            WT[mt][kc] = packf(*(const float4*)wt, *(const float4*)(wt + 4));
        }

    // biases in registers (occupancy is grid-limited; VGPR headroom is free)
    f4_t bAr[4], bBr[4], bTr[4];
#pragma unroll
    for (int mt = 0; mt < 4; mt++) {
        float4 ta = *(const float4*)&bc[ka * 64 + mt * 16 + q * 4];
        float4 tb = *(const float4*)&bc[kb * 64 + mt * 16 + q * 4];
        float4 tt = *(const float4*)&bc[kt * 64 + mt * 16 + q * 4];
        bAr[mt] = f4_t{ta.x, ta.y, ta.z, ta.w};
        bBr[mt] = f4_t{tb.x, tb.y, tb.z, tb.w};
        bTr[mt] = f4_t{tt.x, tt.y, tt.z, tt.w};
    }

    const float* yB = y2 + (size_t)b * CHW_;
    float* oB = outD + (size_t)d * TOT_ + (size_t)b * CHW_;

    __shared__ __align__(16) unsigned short stt[2][130][72];  // +1 zero pad each end
    for (int idx = tid; idx < 2 * 2 * 72; idx += 512) {
        int buf = idx / 144, hi = (idx / 72) & 1, t = idx % 72;
        stt[buf][hi ? 129 : 0][t] = 0;
    }

    // ---- j = 0 : c0 = relu(base col0)
    int c0 = flip ? 127 : 0;
    {
        const unsigned short* sp = base2 + (size_t)(row * 128 + c0) * 64 + q * 16;
        uint4 v0 = relu8(*(const uint4*)sp);
        uint4 v1 = relu8(*(const uint4*)(sp + 8));
        *(uint4*)&stt[0][row + 1][q * 16] = v0;
        *(uint4*)&stt[0][row + 1][q * 16 + 8] = v1;
        float* op = oB + (size_t)(row * 128 + c0) * 64 + q * 16;
        unsigned int w8[8] = {v0.x, v0.y, v0.z, v0.w, v1.x, v1.y, v1.z, v1.w};
#pragma unroll
        for (int t = 0; t < 8; t++) {
            op[2 * t]     = b2f((unsigned short)(w8[t] & 0xffffu));
            op[2 * t + 1] = b2f((unsigned short)(w8[t] >> 16));
        }
    }

    int rsh = row + (down ? -1 : 1);
    rsh = rsh < 0 ? 0 : (rsh > 127 ? 127 : rsh);
    int srow = down ? row : row + 2;   // shifted-state LDS index (incl. +1 pad)
    float gT = (down ? (row == 0) : (row == 127)) ? 0.f : g;

    // prefetch j=1
    uint4 pb0, pb1; float4 yr[4], ys[4];
    {
        int cj1 = flip ? 126 : 1, yc1 = flip ? 127 : 0;
        const unsigned short* sp = base2 + (size_t)(row * 128 + cj1) * 64 + q * 8;
        pb0 = *(const uint4*)sp;
        pb1 = *(const uint4*)(sp + 32);
#pragma unroll
        for (int mt = 0; mt < 4; mt++) {
            yr[mt] = *(const float4*)&yB[(size_t)(row * 128 + yc1) * 64 + mt * 16 + q * 4];
            ys[mt] = *(const float4*)&yB[(size_t)(rsh * 128 + yc1) * 64 + mt * 16 + q * 4];
        }
    }
    LDS_BARRIER();

    for (int j = 1; j < 128; j++) {
        int cj = flip ? 127 - j : j;
        int rd = (j - 1) & 1, wr = j & 1;

        bfrag fb0 = *(const bfrag*)&stt[rd][row + 1][q * 8];
        bfrag fb1 = *(const bfrag*)&stt[rd][row + 1][32 + q * 8];
        bfrag ft0 = *(const bfrag*)&stt[rd][srow][q * 8];
        bfrag ft1 = *(const bfrag*)&stt[rd][srow][32 + q * 8];
        bfrag fa0 = *(const bfrag*)&pb0;
        bfrag fa1 = *(const bfrag*)&pb1;

        f4_t DA[4], DB[4], DT[4];
#pragma unroll
        for (int mt = 0; mt < 4; mt++) {
            DA[mt] = MFMA(WA[mt][0], fa0, bAr[mt], 0, 0, 0);
            DA[mt] = MFMA(WA[mt][1], fa1, DA[mt], 0, 0, 0);
            DB[mt] = MFMA(WB[mt][0], fb0, bBr[mt], 0, 0, 0);
            DB[mt] = MFMA(WB[mt][1], fb1, DB[mt], 0, 0, 0);
            DT[mt] = MFMA(WT[mt][0], ft0, bTr[mt], 0, 0, 0);
            DT[mt] = MFMA(WT[mt][1], ft1, DT[mt], 0, 0, 0);
        }

        // prefetch j+1 (stays in flight across the LDS barrier)
        uint4 nb0, nb1; float4 nyr[4], nys[4];
        if (j < 127) {
            int cjN = flip ? 127 - (j + 1) : j + 1;
            int ycN = flip ? 127 - j : j;
            const unsigned short* sp = base2 + (size_t)(row * 128 + cjN) * 64 + q * 8;
            nb0 = *(const uint4*)sp;
            nb1 = *(const uint4*)(sp + 32);
#pragma unroll
            for (int mt = 0; mt < 4; mt++) {
                nyr[mt] = *(const float4*)&yB[(size_t)(row * 128 + ycN) * 64 + mt * 16 + q * 4];
                nys[mt] = *(const float4*)&yB[(size_t)(rsh * 128 + ycN) * 64 + mt * 16 + q * 4];
            }
        }

        // finalize: h = relu(DA + DB*y_r + gT*DT*y_rsh)
#pragma unroll
        for (int mt = 0; mt < 4; mt++) {
            float yrv[4] = {yr[mt].x, yr[mt].y, yr[mt].z, yr[mt].w};
            float ysv[4] = {ys[mt].x, ys[mt].y, ys[mt].z, ys[mt].w};
            float h[4];
#pragma unroll
            for (int r = 0; r < 4; r++)
                h[r] = fmaxf(DA[mt][r] + DB[mt][r] * yrv[r] + gT * DT[mt][r] * ysv[r], 0.f);
            *(ushort4*)&stt[wr][row + 1][mt * 16 + q * 4] = pack4(h[0], h[1], h[2], h[3]);
            *(float4*)&oB[(size_t)(row * 128 + cj) * 64 + mt * 16 + q * 4] =
                make_float4(h[0], h[1], h[2], h[3]);
        }
        if (j < 127) {
            pb0 = nb0; pb1 = nb1;
#pragma unroll
            for (int mt = 0; mt < 4; mt++) { yr[mt] = nyr[mt]; ys[mt] = nys[mt]; }
        }
        LDS_BARRIER();
    }
}

extern "C" void kernel_launch(void* const* d_in, const int* in_sizes, int n_in,
                              void* d_out, int out_size, void* d_ws, size_t ws_size,
                              hipStream_t stream) {
    const float* x   = (const float*)d_in[0];
    const float* y   = (const float*)d_in[1];
    const float* Wc  = (const float*)d_in[2];
    const float* bc  = (const float*)d_in[3];
    const float* gam = (const float*)d_in[4];
    float* out = (float*)d_out;

    // ws layout (bytes): x2 bf16 (16.8M), y2 fp32 (33.6M), hs2/hn2 bf16 (16.8M ea),
    // outD fp32 x4 dirs (134.2M) => ~218 MB total
    unsigned short* x2 = (unsigned short*)d_ws;
    float* y2 = (float*)d_ws + (size_t)TOT_ / 2;
    unsigned short* hs2 = (unsigned short*)(y2 + (size_t)TOT_);
    unsigned short* hn2 = hs2 + (size_t)TOT_;
    float* outD = (float*)(hn2 + (size_t)TOT_);

    hipLaunchKernelGGL(k_prep, dim3(4096), dim3(256), 0, stream, x, y, y2, x2);
    hipLaunchKernelGGL(k_rowscan, dim3(128), dim3(64), 0, stream, x2, y2, Wc, bc, hs2, hn2);
    hipLaunchKernelGGL(k_colscan, dim3(32), dim3(512), 0, stream, y2, hs2, hn2, Wc, bc, gam, outD);
    hipLaunchKernelGGL(k_tb, dim3(2048), dim3(256), 0, stream,
                       outD, outD + (size_t)TOT_, outD + 2 * (size_t)TOT_,
                       outD + 3 * (size_t)TOT_, out);
}

// Round 2
// 465.937 us; speedup vs baseline: 1.3182x; 1.3182x over previous
//
#include <hip/hip_runtime.h>

// UAG_RNN v6: attack per-CU memory-pipe bound in the scans.
//  - y2 stored bf16 (halves y load bytes; k_prep write halves)
//  - colscan: ys (shifted-row y) served from a double-buffered padded LDS tile
//    staged once per step; yr also read from LDS -> global y loads 1x not 2x
//  - outD stored bf16 (stores halve; k_tb reads bf16)
//  - prefetch issue decoupled: next-column loads issue BEFORE the vmcnt wait
//    of the current consumers (consume-then-reload), so per-step load
//    latencies pipeline instead of serializing.
// B=8, C=64, H=128, W=128.

#define B_ 8
#define C_ 64
#define H_ 128
#define W_ 128
#define HW_ (H_*W_)      // 16384
#define CHW_ (C_*HW_)    // 1048576
#define TOT_ (B_*CHW_)   // 8388608

typedef __attribute__((ext_vector_type(8))) short bfrag;
typedef __attribute__((ext_vector_type(4))) float f4_t;

// LDS-ordering barrier: flush own DS ops, then workgroup barrier. Does NOT
// drain vmcnt — global prefetch loads / stores stay in flight across steps.
#define LDS_BARRIER() do { \
    asm volatile("s_waitcnt lgkmcnt(0)" ::: "memory"); \
    __builtin_amdgcn_s_barrier(); \
} while (0)

// Single-wave LDS ordering point.
#define WAVE_LDS_FENCE() asm volatile("s_waitcnt lgkmcnt(0)" ::: "memory")

__device__ inline unsigned short bfr(float f) {
    unsigned int u = __float_as_uint(f);
    u += 0x7fffu + ((u >> 16) & 1u);
    return (unsigned short)(u >> 16);
}
__device__ inline float b2f(unsigned short u) {
    return __uint_as_float(((unsigned int)u) << 16);
}
__device__ inline bfrag packf(float4 a, float4 b) {
    bfrag r;
    r[0]=(short)bfr(a.x); r[1]=(short)bfr(a.y); r[2]=(short)bfr(a.z); r[3]=(short)bfr(a.w);
    r[4]=(short)bfr(b.x); r[5]=(short)bfr(b.y); r[6]=(short)bfr(b.z); r[7]=(short)bfr(b.w);
    return r;
}
__device__ inline ushort4 pack4(float a, float b, float c, float d) {
    ushort4 r; r.x=bfr(a); r.y=bfr(b); r.z=bfr(c); r.w=bfr(d); return r;
}
__device__ inline unsigned int relu2(unsigned int w) {
    unsigned int lo = (w & 0x8000u) ? 0u : (w & 0xffffu);
    unsigned int hi = (w & 0x80000000u) ? 0u : (w & 0xffff0000u);
    return lo | hi;
}
__device__ inline uint4 relu8(uint4 v) {
    v.x = relu2(v.x); v.y = relu2(v.y); v.z = relu2(v.z); v.w = relu2(v.w);
    return v;
}

#define MFMA __builtin_amdgcn_mfma_f32_16x16x32_bf16

// x,y NCHW fp32 -> NHWC bf16 (x2 / y2b)
__global__ void k_prep(const float* __restrict__ x, const float* __restrict__ y,
                       unsigned short* __restrict__ y2b, unsigned short* __restrict__ x2) {
    __shared__ float t[64][65];
    int blk = blockIdx.x;
    int isx = blk >> 11; blk &= 2047;
    int b = blk >> 8, hw0 = (blk & 255) * 64;
    int cq = threadIdx.x >> 6, lo = threadIdx.x & 63;
    const float* ip = (isx ? x : y) + (size_t)b * CHW_;
#pragma unroll
    for (int p = 0; p < 16; p++) {
        int c = p * 4 + cq;
        t[c][lo] = ip[(size_t)c * HW_ + hw0 + lo];
    }
    __syncthreads();
    unsigned short* op = (isx ? x2 : y2b) + (size_t)b * CHW_;
#pragma unroll
    for (int p = 0; p < 16; p++) {
        int hw = p * 4 + cq;
        op[(size_t)(hw0 + hw) * 64 + lo] = bfr(t[lo][hw]);
    }
}

// sum 4 bf16 NHWC dir buffers -> out NCHW fp32
__global__ void k_tb(const unsigned short* __restrict__ i0, const unsigned short* __restrict__ i1,
                     const unsigned short* __restrict__ i2, const unsigned short* __restrict__ i3,
                     float* __restrict__ outp) {
    __shared__ float t[64][65];
    int blk = blockIdx.x;
    int b = blk >> 8, hw0 = (blk & 255) * 64;
    int tid = threadIdx.x;
    size_t bb = (size_t)b * CHW_;
    int hwi = tid >> 4, c4 = (tid & 15) * 4;
#pragma unroll
    for (int p = 0; p < 4; p++) {
        int hw = p * 16 + hwi;
        size_t s = bb + (size_t)(hw0 + hw) * 64 + c4;
        uint2 u0 = *(const uint2*)(i0 + s);
        uint2 u1 = *(const uint2*)(i1 + s);
        uint2 u2 = *(const uint2*)(i2 + s);
        uint2 u3 = *(const uint2*)(i3 + s);
        float v0 = b2f((unsigned short)(u0.x & 0xffffu)) + b2f((unsigned short)(u1.x & 0xffffu))
                 + b2f((unsigned short)(u2.x & 0xffffu)) + b2f((unsigned short)(u3.x & 0xffffu));
        float v1 = b2f((unsigned short)(u0.x >> 16)) + b2f((unsigned short)(u1.x >> 16))
                 + b2f((unsigned short)(u2.x >> 16)) + b2f((unsigned short)(u3.x >> 16));
        float v2 = b2f((unsigned short)(u0.y & 0xffffu)) + b2f((unsigned short)(u1.y & 0xffffu))
                 + b2f((unsigned short)(u2.y & 0xffffu)) + b2f((unsigned short)(u3.y & 0xffffu));
        float v3 = b2f((unsigned short)(u0.y >> 16)) + b2f((unsigned short)(u1.y >> 16))
                 + b2f((unsigned short)(u2.y >> 16)) + b2f((unsigned short)(u3.y >> 16));
        t[hw][c4 + 0] = v0; t[hw][c4 + 1] = v1; t[hw][c4 + 2] = v2; t[hw][c4 + 3] = v3;
    }
    __syncthreads();
    float* op = outp + bb;
    int cq = tid >> 6, lo = tid & 63;
#pragma unroll
    for (int p = 0; p < 16; p++) {
        int c = p * 4 + cq;
        op[(size_t)c * HW_ + hw0 + lo] = t[lo][c];
    }
}

// Row scans: grid 128 = s(2) x b(8) x wb(8 of width 16). 1 wave/block.
__global__ __launch_bounds__(64) void k_rowscan(
        const unsigned short* __restrict__ x2, const unsigned short* __restrict__ y2b,
        const float* __restrict__ Wc, const float* __restrict__ bc,
        unsigned short* __restrict__ hs2, unsigned short* __restrict__ hn2) {
    int bid = blockIdx.x;
    int s = bid >> 6, b = (bid >> 3) & 7, wb = bid & 7;
    int w0 = wb * 16;
    int lane = threadIdx.x, q = lane >> 4, n = lane & 15;
    int ka = s ? 8 : 0, kb = ka + 1;

    bfrag WaF[4][2], WbF[4][2];
#pragma unroll
    for (int mt = 0; mt < 4; mt++)
#pragma unroll
        for (int kc = 0; kc < 2; kc++) {
            const float* wp = Wc + (size_t)(ka * 64 + mt * 16 + n) * 64 + kc * 32 + q * 8;
            WaF[mt][kc] = packf(*(const float4*)wp, *(const float4*)(wp + 4));
            const float* wq2 = Wc + (size_t)(kb * 64 + mt * 16 + n) * 64 + kc * 32 + q * 8;
            WbF[mt][kc] = packf(*(const float4*)wq2, *(const float4*)(wq2 + 4));
        }
    f4_t baR[4], bbR[4];
#pragma unroll
    for (int mt = 0; mt < 4; mt++) {
        float4 ta = *(const float4*)&bc[ka * 64 + mt * 16 + q * 4];
        float4 tb = *(const float4*)&bc[kb * 64 + mt * 16 + q * 4];
        baR[mt] = f4_t{ta.x, ta.y, ta.z, ta.w};
        bbR[mt] = f4_t{tb.x, tb.y, tb.z, tb.w};
    }

    const unsigned short* xb = x2 + (size_t)b * CHW_;
    const unsigned short* yb = y2b + (size_t)b * CHW_;
    unsigned short* dT = (s ? hn2 : hs2) + (size_t)b * CHW_;

    __shared__ __align__(16) unsigned short stt[2][16][72];

    int row0 = s ? 127 : 0;
    {
        const unsigned short* sp = xb + (size_t)(row0 * 128 + w0 + n) * 64 + q * 16;
        uint4 v0 = *(const uint4*)sp;
        uint4 v1 = *(const uint4*)(sp + 8);
        if (s) { v0 = relu8(v0); v1 = relu8(v1); }
        *(uint4*)&stt[0][n][q * 16] = v0;
        *(uint4*)&stt[0][n][q * 16 + 8] = v1;
        unsigned short* op = dT + (size_t)(row0 * 128 + w0 + n) * 64 + q * 16;
        *(uint4*)op = v0;
        *(uint4*)(op + 8) = v1;
    }

    // prefetch i=1
    uint4 xf0, xf1; ushort4 yv[4];
    {
        int row1 = s ? 126 : 1;
        const unsigned short* sp = xb + (size_t)(row1 * 128 + w0 + n) * 64 + q * 8;
        xf0 = *(const uint4*)sp;
        xf1 = *(const uint4*)(sp + 32);
#pragma unroll
        for (int mt = 0; mt < 4; mt++)
            yv[mt] = *(const ushort4*)&yb[(size_t)(row0 * 128 + w0 + n) * 64 + mt * 16 + q * 4];
    }
    WAVE_LDS_FENCE();

    for (int i = 1; i < 128; i++) {
        int row = s ? 127 - i : i;
        int rd = (i - 1) & 1, wr = i & 1;

        bfrag fb0 = *(const bfrag*)&stt[rd][n][q * 8];
        bfrag fb1 = *(const bfrag*)&stt[rd][n][32 + q * 8];
        bfrag fa0 = *(const bfrag*)&xf0;
        bfrag fa1 = *(const bfrag*)&xf1;

        // EARLY prefetch issue (before MFMA's vmcnt wait on xf/yv)
        uint4 xn0, xn1; ushort4 yn[4];
        if (i < 127) {
            int rowN = s ? 127 - (i + 1) : i + 1;
            int yrowN = s ? rowN + 1 : rowN - 1;
            const unsigned short* sp = xb + (size_t)(rowN * 128 + w0 + n) * 64 + q * 8;
            xn0 = *(const uint4*)sp;
            xn1 = *(const uint4*)(sp + 32);
#pragma unroll
            for (int mt = 0; mt < 4; mt++)
                yn[mt] = *(const ushort4*)&yb[(size_t)(yrowN * 128 + w0 + n) * 64 + mt * 16 + q * 4];
        }

        f4_t DA[4], DB[4];
#pragma unroll
        for (int mt = 0; mt < 4; mt++) {
            DA[mt] = MFMA(WaF[mt][0], fa0, baR[mt], 0, 0, 0);
            DA[mt] = MFMA(WaF[mt][1], fa1, DA[mt], 0, 0, 0);
            DB[mt] = MFMA(WbF[mt][0], fb0, bbR[mt], 0, 0, 0);
            DB[mt] = MFMA(WbF[mt][1], fb1, DB[mt], 0, 0, 0);
        }

#pragma unroll
        for (int mt = 0; mt < 4; mt++) {
            float h0 = fmaxf(DA[mt][0] + DB[mt][0] * b2f(yv[mt].x), 0.f);
            float h1 = fmaxf(DA[mt][1] + DB[mt][1] * b2f(yv[mt].y), 0.f);
            float h2 = fmaxf(DA[mt][2] + DB[mt][2] * b2f(yv[mt].z), 0.f);
            float h3 = fmaxf(DA[mt][3] + DB[mt][3] * b2f(yv[mt].w), 0.f);
            ushort4 pk = pack4(h0, h1, h2, h3);
            *(ushort4*)&stt[wr][n][mt * 16 + q * 4] = pk;
            *(ushort4*)&dT[(size_t)(row * 128 + w0 + n) * 64 + mt * 16 + q * 4] = pk;
        }
        if (i < 127) {
            xf0 = xn0; xf1 = xn1;
#pragma unroll
            for (int mt = 0; mt < 4; mt++) yv[mt] = yn[mt];
        }
        WAVE_LDS_FENCE();
    }
}

// Col scans: grid 32 = d(4) x b(8). 512 threads = 8 waves.
// y column staged in padded LDS (dbuf); yr+ys read from LDS; outputs bf16.
__global__ __launch_bounds__(512, 2) void k_colscan(
        const unsigned short* __restrict__ y2b,
        const unsigned short* __restrict__ hs2, const unsigned short* __restrict__ hn2,
        const float* __restrict__ Wc, const float* __restrict__ bc,
        const float* __restrict__ gam,
        unsigned short* __restrict__ outD) {
    int bid = blockIdx.x;
    int d = bid >> 3, b = bid & 7;
    int tid = threadIdx.x;
    int wave = tid >> 6, lane = tid & 63, q = lane >> 4, n = lane & 15;
    int row = wave * 16 + n;
    int down = (d < 2) ? 1 : 0;
    int flip = d & 1;
    const unsigned short* base2 = ((d < 2) ? hs2 : hn2) + (size_t)b * CHW_;
    int kt, ka, kb;
    if (d == 0)      { kt = 2;  ka = 3;  kb = 4;  }
    else if (d == 1) { kt = 5;  ka = 6;  kb = 7;  }
    else if (d == 2) { kt = 10; ka = 11; kb = 12; }
    else             { kt = 13; ka = 14; kb = 15; }
    float g = gam[d];

    bfrag WA[4][2], WB[4][2], WT[4][2];
#pragma unroll
    for (int mt = 0; mt < 4; mt++)
#pragma unroll
        for (int kc = 0; kc < 2; kc++) {
            const float* wa = Wc + (size_t)(ka * 64 + mt * 16 + n) * 64 + kc * 32 + q * 8;
            const float* wb = Wc + (size_t)(kb * 64 + mt * 16 + n) * 64 + kc * 32 + q * 8;
            const float* wt = Wc + (size_t)(kt * 64 + mt * 16 + n) * 64 + kc * 32 + q * 8;
            WA[mt][kc] = packf(*(const float4*)wa, *(const float4*)(wa + 4));
            WB[mt][kc] = packf(*(const float4*)wb, *(const float4*)(wb + 4));
            WT[mt][kc] = packf(*(const float4*)wt, *(const float4*)(wt + 4));
        }
    f4_t bAr[4], bBr[4], bTr[4];
#pragma unroll
    for (int mt = 0; mt < 4; mt++) {
        float4 ta = *(const float4*)&bc[ka * 64 + mt * 16 + q * 4];
        float4 tb = *(const float4*)&bc[kb * 64 + mt * 16 + q * 4];
        float4 tt = *(const float4*)&bc[kt * 64 + mt * 16 + q * 4];
        bAr[mt] = f4_t{ta.x, ta.y, ta.z, ta.w};
        bBr[mt] = f4_t{tb.x, tb.y, tb.z, tb.w};
        bTr[mt] = f4_t{tt.x, tt.y, tt.z, tt.w};
    }

    const unsigned short* yB = y2b + (size_t)b * CHW_;
    unsigned short* oB = outD + (size_t)d * TOT_ + (size_t)b * CHW_;

    __shared__ __align__(16) unsigned short stt[2][130][72];
    __shared__ __align__(16) unsigned short yl[2][130][72];
    for (int idx = tid; idx < 2 * 2 * 72; idx += 512) {
        int buf = idx / 144, hi = (idx / 72) & 1, t = idx % 72;
        stt[buf][hi ? 129 : 0][t] = 0;
        yl[buf][hi ? 129 : 0][t] = 0;
    }

    // ---- j = 0 : c0 = relu(base col0)
    int c0 = flip ? 127 : 0;
    {
        const unsigned short* sp = base2 + (size_t)(row * 128 + c0) * 64 + q * 16;
        uint4 v0 = relu8(*(const uint4*)sp);
        uint4 v1 = relu8(*(const uint4*)(sp + 8));
        *(uint4*)&stt[0][row + 1][q * 16] = v0;
        *(uint4*)&stt[0][row + 1][q * 16 + 8] = v1;
        unsigned short* op = oB + (size_t)(row * 128 + c0) * 64 + q * 16;
        *(uint4*)op = v0;
        *(uint4*)(op + 8) = v1;
    }

    int srow = down ? row : row + 2;   // shifted index into padded LDS rows
    float gT = (down ? (row == 0) : (row == 127)) ? 0.f : g;

    // stage y col for step 1 directly into yl[0]
    {
        int yc1 = flip ? 127 : 0;
        const unsigned short* yp = yB + (size_t)(row * 128 + yc1) * 64 + q * 16;
        uint4 w0_ = *(const uint4*)yp;
        uint4 w1_ = *(const uint4*)(yp + 8);
        *(uint4*)&yl[0][row + 1][q * 16] = w0_;
        *(uint4*)&yl[0][row + 1][q * 16 + 8] = w1_;
    }

    // prefetch regs: pb = base col c(1); yg = y col yc(2)
    uint4 pb0, pb1, yg0, yg1;
    {
        int c1 = flip ? 126 : 1;
        const unsigned short* sp = base2 + (size_t)(row * 128 + c1) * 64 + q * 8;
        pb0 = *(const uint4*)sp;
        pb1 = *(const uint4*)(sp + 32);
        int yc2 = flip ? 126 : 1;
        const unsigned short* yp = yB + (size_t)(row * 128 + yc2) * 64 + q * 16;
        yg0 = *(const uint4*)yp;
        yg1 = *(const uint4*)(yp + 8);
    }
    LDS_BARRIER();

    for (int j = 1; j < 128; j++) {
        int cj = flip ? 127 - j : j;
        int rd = (j - 1) & 1, wr = j & 1;

        // LDS reads: state frags + y (own row & shifted row)
        bfrag fb0 = *(const bfrag*)&stt[rd][row + 1][q * 8];
        bfrag fb1 = *(const bfrag*)&stt[rd][row + 1][32 + q * 8];
        bfrag ft0 = *(const bfrag*)&stt[rd][srow][q * 8];
        bfrag ft1 = *(const bfrag*)&stt[rd][srow][32 + q * 8];
        ushort4 yru[4], ysu[4];
#pragma unroll
        for (int mt = 0; mt < 4; mt++) {
            yru[mt] = *(const ushort4*)&yl[rd][row + 1][mt * 16 + q * 4];
            ysu[mt] = *(const ushort4*)&yl[rd][srow][mt * 16 + q * 4];
        }
        bfrag fa0 = *(const bfrag*)&pb0;
        bfrag fa1 = *(const bfrag*)&pb1;

        f4_t DA[4], DB[4], DT[4];
#pragma unroll
        for (int mt = 0; mt < 4; mt++) {
            DA[mt] = MFMA(WA[mt][0], fa0, bAr[mt], 0, 0, 0);
            DA[mt] = MFMA(WA[mt][1], fa1, DA[mt], 0, 0, 0);
            DB[mt] = MFMA(WB[mt][0], fb0, bBr[mt], 0, 0, 0);
            DB[mt] = MFMA(WB[mt][1], fb1, DB[mt], 0, 0, 0);
            DT[mt] = MFMA(WT[mt][0], ft0, bTr[mt], 0, 0, 0);
            DT[mt] = MFMA(WT[mt][1], ft1, DT[mt], 0, 0, 0);
        }

        // reload pb <- base col c(j+1)  (consume-then-reload, stays in flight)
        if (j < 127) {
            int cN = flip ? 126 - j : j + 1;
            const unsigned short* sp = base2 + (size_t)(row * 128 + cN) * 64 + q * 8;
            pb0 = *(const uint4*)sp;
            pb1 = *(const uint4*)(sp + 32);
        }
        // ds_write staged y col yc(j+1) -> yl[wr]; reload yg <- yc(j+2)
        if (j < 127) {
            *(uint4*)&yl[wr][row + 1][q * 16] = yg0;
            *(uint4*)&yl[wr][row + 1][q * 16 + 8] = yg1;
        }
        if (j < 126) {
            int ycN2 = flip ? 126 - j : j + 1;
            const unsigned short* yp = yB + (size_t)(row * 128 + ycN2) * 64 + q * 16;
            yg0 = *(const uint4*)yp;
            yg1 = *(const uint4*)(yp + 8);
        }

        // finalize: h = relu(DA + DB*yr + gT*DT*ys)
#pragma unroll
        for (int mt = 0; mt < 4; mt++) {
            float yrv[4] = {b2f(yru[mt].x), b2f(yru[mt].y), b2f(yru[mt].z), b2f(yru[mt].w)};
            float ysv[4] = {b2f(ysu[mt].x), b2f(ysu[mt].y), b2f(ysu[mt].z), b2f(ysu[mt].w)};
            float h[4];
#pragma unroll
            for (int r = 0; r < 4; r++)
                h[r] = fmaxf(DA[mt][r] + DB[mt][r] * yrv[r] + gT * DT[mt][r] * ysv[r], 0.f);
            ushort4 pk = pack4(h[0], h[1], h[2], h[3]);
            *(ushort4*)&stt[wr][row + 1][mt * 16 + q * 4] = pk;
            *(ushort4*)&oB[(size_t)(row * 128 + cj) * 64 + mt * 16 + q * 4] = pk;
        }
        LDS_BARRIER();
    }
}

extern "C" void kernel_launch(void* const* d_in, const int* in_sizes, int n_in,
                              void* d_out, int out_size, void* d_ws, size_t ws_size,
                              hipStream_t stream) {
    const float* x   = (const float*)d_in[0];
    const float* y   = (const float*)d_in[1];
    const float* Wc  = (const float*)d_in[2];
    const float* bc  = (const float*)d_in[3];
    const float* gam = (const float*)d_in[4];
    float* out = (float*)d_out;

    // ws layout (all bf16): x2, y2b, hs2, hn2 (TOT_ each), outD (4x TOT_)
    // total = 8 * TOT_ * 2B = 134 MB
    unsigned short* x2  = (unsigned short*)d_ws;
    unsigned short* y2b = x2 + (size_t)TOT_;
    unsigned short* hs2 = y2b + (size_t)TOT_;
    unsigned short* hn2 = hs2 + (size_t)TOT_;
    unsigned short* outD = hn2 + (size_t)TOT_;

    hipLaunchKernelGGL(k_prep, dim3(4096), dim3(256), 0, stream, x, y, y2b, x2);
    hipLaunchKernelGGL(k_rowscan, dim3(128), dim3(64), 0, stream, x2, y2b, Wc, bc, hs2, hn2);
    hipLaunchKernelGGL(k_colscan, dim3(32), dim3(512), 0, stream, y2b, hs2, hn2, Wc, bc, gam, outD);
    hipLaunchKernelGGL(k_tb, dim3(2048), dim3(256), 0, stream,
                       outD, outD + (size_t)TOT_, outD + 2 * (size_t)TOT_,
                       outD + 3 * (size_t)TOT_, out);
}